// Round 5
// baseline (498.961 us; speedup 1.0000x reference)
//
#include <hip/hip_runtime.h>
#include <hip/hip_bf16.h>

#define N_    32
#define T_    1600
#define C_    1024
#define S_    200
#define L_    401       // 2*S+1
#define LP_   512       // padded
#define BLANK_ 4
#define LN2_  0.69314718055994531f
#define L2E_  1.44269504088896341f
#define DPF   8

#if __has_builtin(__builtin_amdgcn_exp2f)
#define EXP2(x) __builtin_amdgcn_exp2f(x)
#else
#define EXP2(x) exp2f(x)
#endif
#if __has_builtin(__builtin_amdgcn_rcpf)
#define RCP(x) __builtin_amdgcn_rcpf(x)
#else
#define RCP(x) (1.0f / (x))
#endif

// LDS-only barrier: s_waitcnt lgkmcnt(0) + s_barrier. __syncthreads() would
// also drain vmcnt(0), flushing the global prefetch ring every step.
#define BAR() asm volatile("s_waitcnt lgkmcnt(0)\n\ts_barrier" ::: "memory")

// Kernel 1: one wave per (n,t) row. Wave-shuffle softmax, row staged in LDS,
// gather ext-label classes, write LINEAR probabilities P[n][t][l].
// Junk/pad positions (l > 2*tgt_len[n]) are zeroed: their alphas stay exactly
// 0 in k_ctc (never pollute renorm max; pad 511 doubles as wave0's zero
// boundary source).
__global__ __launch_bounds__(256)
void k_softmax_gather(const float* __restrict__ logits,
                      const int* __restrict__ targets,
                      const int* __restrict__ tgt_len,
                      float* __restrict__ P) {
  const int row  = blockIdx.x * 4 + (threadIdx.x >> 6);  // n*T_ + t
  const int lane = threadIdx.x & 63;
  const int wv   = threadIdx.x >> 6;
  const int n    = row / T_;
  const float* x = logits + (size_t)row * C_;
  __shared__ float sh[4][C_];

  float4 v[4];
#pragma unroll
  for (int i = 0; i < 4; ++i)
    v[i] = reinterpret_cast<const float4*>(x)[i * 64 + lane];

  float mx = v[0].x;
#pragma unroll
  for (int i = 0; i < 4; ++i)
    mx = fmaxf(mx, fmaxf(fmaxf(v[i].x, v[i].y), fmaxf(v[i].z, v[i].w)));
#pragma unroll
  for (int i = 1; i < 64; i <<= 1) mx = fmaxf(mx, __shfl_xor(mx, i));

  float s = 0.0f;
#pragma unroll
  for (int i = 0; i < 4; ++i) {
    s += EXP2((v[i].x - mx) * L2E_) + EXP2((v[i].y - mx) * L2E_)
       + EXP2((v[i].z - mx) * L2E_) + EXP2((v[i].w - mx) * L2E_);
  }
#pragma unroll
  for (int i = 1; i < 64; i <<= 1) s += __shfl_xor(s, i);
  float rz = RCP(s);

#pragma unroll
  for (int i = 0; i < 4; ++i)
    reinterpret_cast<float4*>(sh[wv])[i * 64 + lane] = v[i];
  __syncthreads();

  const int* tg = targets + n * S_;
  const int lmax = 2 * tgt_len[n];   // live region: l in [0, 2*tl]
  float* out = P + (size_t)row * LP_;
#pragma unroll
  for (int i = 0; i < 8; ++i) {
    int l = lane + i * 64;
    float p = 0.0f;
    if (l <= lmax) {
      int c = (l & 1) ? tg[(l - 1) >> 1] : BLANK_;
      p = EXP2((sh[wv][c] - mx) * L2E_) * rz;
    }
    out[l] = p;
  }
}

// Kernel 2: f64 linear-space CTC forward, TWO waves per sequence.
// Wave w owns l in [256w, 256w+256), 4 contiguous positions per lane.
// Even-l positions have sk==0 structurally -> add+mul only (10 f64 ops/lane).
// Cross-wave boundary = one double per step via parity LDS slots + raw
// lgkm-only barrier. Block-wide renorm by 2^R every 32 steps.
__global__ __launch_bounds__(128)
void k_ctc(const float* __restrict__ P,
           const int* __restrict__ targets,
           const int* __restrict__ in_len,
           const int* __restrict__ tgt_len,
           float* __restrict__ nll_out) {
  const int n = blockIdx.x;
  const int tid = threadIdx.x;
  const int w = tid >> 6;
  const int lane = tid & 63;
  const int Tn = in_len[n];
  const float* g = P + (size_t)n * T_ * LP_;
  const int base = (w << 8) + (lane << 2);   // first of this lane's 4 positions

  __shared__ double slot[2][2];   // [t&1][wave] boundary a3
  __shared__ int rl[2];           // renorm wave maxima
  __shared__ double sa[LP_];      // final alpha dump

  const int* tg = targets + n * S_;
  // odd positions j=1 (m1) and j=3 (m3=m1+1): skip iff label != previous label
  const int m1 = (w << 7) + (lane << 1);
  const int mm = m1 > 0 ? m1 : 1;            // avoid tg[-1] speculation
  double sk1 = (m1 >= 1 && m1 < S_ && tg[mm] != tg[mm - 1]) ? 1.0 : 0.0;
  const int m3 = m1 + 1;                     // >= 1 always
  double sk3 = (m3 < S_ && tg[m3] != tg[m3 - 1]) ? 1.0 : 0.0;

  double a0 = 0.0, a1 = 0.0, a2 = 0.0, a3 = 0.0;
  double up = 0.0;                 // alpha(t-1) at base-1 (from prev lane/wave)
  if (tid == 0) { a0 = (double)g[0]; a1 = (double)g[1]; }
  int Etot = 0;                    // true alpha = a * 2^Etot (block-uniform)

  const float* gl = g + base;
  float4 b[DPF];
#pragma unroll
  for (int d = 0; d < DPF; ++d) {
    int tt = 1 + d;
    b[d] = *reinterpret_cast<const float4*>(gl + (size_t)tt * LP_);
  }

  const int src = (lane + 63) & 63;

  auto step = [&](int t, const float4& pv) {
    double p0 = (double)pv.x, p1 = (double)pv.y;
    double p2 = (double)pv.z, p3 = (double)pv.w;
    double a3n = (a3 + a2 + sk3 * a1) * p3;
    double a2n = (a2 + a1) * p2;            // even l: sk==0
    double a1n = (a1 + a0 + sk1 * up) * p1;
    double a0n = (a0 + up) * p0;            // even l: sk==0
    if (lane == 63) slot[t & 1][w] = a3n;   // publish boundary alpha(t)
    BAR();
    double bd = slot[t & 1][w ^ 1];         // other wave's boundary
    double sh = __shfl(a3n, src);           // prev lane's a3(t)
    // lane0: wave1 takes wave0's boundary; wave0 takes wave1's l=511 pad
    // alpha which is identically 0 (p[511]==0) == the correct "no predecessor".
    up = (lane == 0) ? bd : sh;
    a0 = a0n; a1 = a1n; a2 = a2n; a3 = a3n;
  };

  auto renorm = [&]() {
    int h = max(max(__double2hiint(a0), __double2hiint(a1)),
                max(__double2hiint(a2), __double2hiint(a3)));
#pragma unroll
    for (int i = 1; i < 64; i <<= 1) h = max(h, __shfl_xor(h, i));
    if (lane == 0) rl[w] = h;
    BAR();
    int hb = max(rl[0], rl[1]);
    int R = 1021 - (hb >> 20);   // scale block max into [2^-2, 2^-1)
    a0 = ldexp(a0, R); a1 = ldexp(a1, R);
    a2 = ldexp(a2, R); a3 = ldexp(a3, R);
    up = ldexp(up, R);           // boundary value rides in the same frame!
    Etot -= R;
  };

  int t = 1;
  const int nsteps = Tn - 1;
  const int nfull = (nsteps / DPF) * DPF;
  int blk = 0;
  for (int s = 0; s < nfull; s += DPF) {
#pragma unroll
    for (int d = 0; d < DPF; ++d) {
      step(t, b[d]);
      int tt = t + DPF; if (tt > T_ - 1) tt = T_ - 1;  // clamped rows unused
      b[d] = *reinterpret_cast<const float4*>(gl + (size_t)tt * LP_);
      ++t;
    }
    if ((++blk & 3) == 0) renorm();   // every 32 steps; max gap 39 < f64 range
  }
#pragma unroll
  for (int d = 0; d < DPF - 1; ++d) {
    if (t < Tn) { step(t, b[d]); ++t; }   // t, Tn block-uniform -> barriers match
  }

  sa[base + 0] = a0; sa[base + 1] = a1;
  sa[base + 2] = a2; sa[base + 3] = a3;
  __syncthreads();
  if (tid == 0) {
    int tl = tgt_len[n];
    double v = sa[2 * tl - 1] + sa[2 * tl];
    int ee;
    double m = frexp(v, &ee);
    nll_out[n] = -LN2_ * ((float)(Etot + ee) + log2f((float)m));
  }
}

__global__ void k_final(const float* __restrict__ nll,
                        const int* __restrict__ tgt_len,
                        float* __restrict__ out) {
  int lane = threadIdx.x;
  float v = 0.0f;
  if (lane < N_) v = nll[lane] / (float)tgt_len[lane];
#pragma unroll
  for (int i = 1; i < 64; i <<= 1) v += __shfl_xor(v, i);
  if (lane == 0) out[0] = v * (1.0f / N_);
}

__global__ void k_sentinel(float* out) { out[0] = -12345.0f; }

extern "C" void kernel_launch(void* const* d_in, const int* in_sizes, int n_in,
                              void* d_out, int out_size, void* d_ws, size_t ws_size,
                              hipStream_t stream) {
  const float* logits = (const float*)d_in[0];
  const int* targets  = (const int*)d_in[1];
  const int* in_len   = (const int*)d_in[2];
  const int* tgt_len  = (const int*)d_in[3];
  float* out = (float*)d_out;

  size_t gbytes = (size_t)N_ * T_ * LP_ * sizeof(float);  // ~104.9 MB
  if (ws_size < gbytes + 256) {
    k_sentinel<<<1, 1, 0, stream>>>(out);
    return;
  }
  float* G = (float*)d_ws;
  float* nll = (float*)((char*)d_ws + gbytes);

  k_softmax_gather<<<(N_ * T_) / 4, 256, 0, stream>>>(logits, targets, tgt_len, G);
  k_ctc<<<N_, 128, 0, stream>>>(G, targets, in_len, tgt_len, nll);
  k_final<<<1, 64, 0, stream>>>(nll, tgt_len, out);
}

// Round 6
// 457.748 us; speedup vs baseline: 1.0900x; 1.0900x over previous
//
#include <hip/hip_runtime.h>
#include <hip/hip_bf16.h>

#define N_    32
#define T_    1600
#define C_    1024
#define S_    200
#define L_    401       // 2*S+1
#define LP_   512       // padded
#define BLANK_ 4
#define LN2_  0.69314718055994531f
#define L2E_  1.44269504088896341f
#define DPF   8

#if __has_builtin(__builtin_amdgcn_exp2f)
#define EXP2(x) __builtin_amdgcn_exp2f(x)
#else
#define EXP2(x) exp2f(x)
#endif
#if __has_builtin(__builtin_amdgcn_rcpf)
#define RCP(x) __builtin_amdgcn_rcpf(x)
#else
#define RCP(x) (1.0f / (x))
#endif

// Kernel 1: one wave per (n,t) row. Wave-shuffle softmax, row staged in LDS,
// gather ext-label classes, write LINEAR probabilities P[n][t][l].
// Junk positions (l > 2*tgt_len[n], never read) are zeroed so their alphas
// stay exactly 0 and never pollute the renorm max in k_ctc.
__global__ __launch_bounds__(256)
void k_softmax_gather(const float* __restrict__ logits,
                      const int* __restrict__ targets,
                      const int* __restrict__ tgt_len,
                      float* __restrict__ P) {
  const int row  = blockIdx.x * 4 + (threadIdx.x >> 6);  // n*T_ + t
  const int lane = threadIdx.x & 63;
  const int wv   = threadIdx.x >> 6;
  const int n    = row / T_;
  const float* x = logits + (size_t)row * C_;
  __shared__ float sh[4][C_];

  float4 v[4];
#pragma unroll
  for (int i = 0; i < 4; ++i)
    v[i] = reinterpret_cast<const float4*>(x)[i * 64 + lane];

  float mx = v[0].x;
#pragma unroll
  for (int i = 0; i < 4; ++i)
    mx = fmaxf(mx, fmaxf(fmaxf(v[i].x, v[i].y), fmaxf(v[i].z, v[i].w)));
#pragma unroll
  for (int i = 1; i < 64; i <<= 1) mx = fmaxf(mx, __shfl_xor(mx, i));

  float s = 0.0f;
#pragma unroll
  for (int i = 0; i < 4; ++i) {
    s += EXP2((v[i].x - mx) * L2E_) + EXP2((v[i].y - mx) * L2E_)
       + EXP2((v[i].z - mx) * L2E_) + EXP2((v[i].w - mx) * L2E_);
  }
#pragma unroll
  for (int i = 1; i < 64; i <<= 1) s += __shfl_xor(s, i);
  float rz = RCP(s);

#pragma unroll
  for (int i = 0; i < 4; ++i)
    reinterpret_cast<float4*>(sh[wv])[i * 64 + lane] = v[i];
  __syncthreads();

  const int* tg = targets + n * S_;
  const int lmax = 2 * tgt_len[n];   // live region: l in [0, 2*tl]
  float* out = P + (size_t)row * LP_;
#pragma unroll
  for (int i = 0; i < 8; ++i) {
    int l = lane + i * 64;
    float p = 0.0f;
    if (l <= lmax) {
      int c = (l & 1) ? tg[(l - 1) >> 1] : BLANK_;
      p = EXP2((sh[wv][c] - mx) * L2E_) * rz;
    }
    out[l] = p;
  }
}

// Kernel 2: f64 linear-space CTC forward, ONE wave per sequence (R5 taught:
// per-step cross-wave barriers cost what they save). Lane owns 8 contiguous
// positions. Even positions (blanks) never skip -> add+mul only; only ONE
// cross-lane value per step (alpha[l-1] for j=0), shuffled one step AHEAD so
// bpermute latency hides under the f64 issue stream.
__global__ __launch_bounds__(64)
void k_ctc(const float* __restrict__ P,
           const int* __restrict__ targets,
           const int* __restrict__ in_len,
           const int* __restrict__ tgt_len,
           float* __restrict__ nll_out) {
  const int n = blockIdx.x;
  const int lane = threadIdx.x;
  const int Tn = in_len[n];
  const float* g = P + (size_t)n * T_ * LP_;
  const int* tg = targets + n * S_;

  // skip multipliers for odd positions j=1,3,5,7 -> label index m0+0..3
  const int m0 = lane * 4;
  auto skv = [&](int m) -> double {
    int mi = (m >= 1 && m < S_) ? m : 1;     // clamp: no OOB read
    return (m >= 1 && m < S_ && tg[mi] != tg[mi - 1]) ? 1.0 : 0.0;
  };
  const double sk1 = skv(m0), sk3 = skv(m0 + 1);
  const double sk5 = skv(m0 + 2), sk7 = skv(m0 + 3);

  double a0 = 0.0, a1 = 0.0, a2 = 0.0, a3 = 0.0;
  double a4 = 0.0, a5 = 0.0, a6 = 0.0, a7 = 0.0;
  double up = 0.0;   // alpha(t-1, lane*8 - 1): shuffled during previous step
  if (lane == 0) { a0 = (double)g[0]; a1 = (double)g[1]; }
  int Etot = 0;      // true alpha = a * 2^Etot (wave-uniform)

  const float* gl = g + lane * 8;
  float4 bA[DPF], bB[DPF];
#pragma unroll
  for (int d = 0; d < DPF; ++d) {
    int tt = 1 + d;
    bA[d] = *reinterpret_cast<const float4*>(gl + (size_t)tt * LP_);
    bB[d] = *reinterpret_cast<const float4*>(gl + (size_t)tt * LP_ + 4);
  }

  const int src = (lane + 63) & 63;

  auto step = [&](const float4& A, const float4& B) {
    // a7n/a6n first: lane-local only -> shuffle for NEXT step issues early
    double a7n = (a7 + a6 + sk7 * a5) * (double)B.w;
    double a6n = (a6 + a5) * (double)B.z;
    double upn = __shfl(a7n, src);           // consumed next step
    double a5n = (a5 + a4 + sk5 * a3) * (double)B.y;
    double a4n = (a4 + a3) * (double)B.x;
    double a3n = (a3 + a2 + sk3 * a1) * (double)A.w;
    double a2n = (a2 + a1) * (double)A.z;
    double a1n = (a1 + a0 + sk1 * up) * (double)A.y;  // up: already in regs
    double a0n = (a0 + up) * (double)A.x;             // even: no skip ever
    if (lane == 0) upn = 0.0;                // no predecessor (R1 lesson)
    a0 = a0n; a1 = a1n; a2 = a2n; a3 = a3n;
    a4 = a4n; a5 = a5n; a6 = a6n; a7 = a7n;
    up = upn;
  };

  auto renorm = [&]() {
    int h = max(max(max(__double2hiint(a0), __double2hiint(a1)),
                    max(__double2hiint(a2), __double2hiint(a3))),
                max(max(__double2hiint(a4), __double2hiint(a5)),
                    max(__double2hiint(a6), __double2hiint(a7))));
#pragma unroll
    for (int i = 1; i < 64; i <<= 1) h = max(h, __shfl_xor(h, i));
    int R = 1021 - (h >> 20);   // scale wave max into [2^-2, 2^-1)
    a0 = ldexp(a0, R); a1 = ldexp(a1, R); a2 = ldexp(a2, R); a3 = ldexp(a3, R);
    a4 = ldexp(a4, R); a5 = ldexp(a5, R); a6 = ldexp(a6, R); a7 = ldexp(a7, R);
    up = ldexp(up, R);          // pipelined boundary value rides along
    Etot -= R;
  };

  int t = 1;
  const int nsteps = Tn - 1;
  const int nfull = (nsteps / DPF) * DPF;
  int blk = 0;
  for (int s = 0; s < nfull; s += DPF) {
#pragma unroll
    for (int d = 0; d < DPF; ++d) {
      step(bA[d], bB[d]);
      int tt = t + DPF; if (tt > T_ - 1) tt = T_ - 1;  // clamped rows unused
      bA[d] = *reinterpret_cast<const float4*>(gl + (size_t)tt * LP_);
      bB[d] = *reinterpret_cast<const float4*>(gl + (size_t)tt * LP_ + 4);
      ++t;
    }
    if ((++blk & 3) == 0) renorm();   // every 32 steps; max gap 39 < f64 range
  }
#pragma unroll
  for (int d = 0; d < DPF - 1; ++d) {
    if (t < Tn) { step(bA[d], bB[d]); ++t; }
  }

  __shared__ double sa[LP_];
  sa[lane * 8 + 0] = a0; sa[lane * 8 + 1] = a1;
  sa[lane * 8 + 2] = a2; sa[lane * 8 + 3] = a3;
  sa[lane * 8 + 4] = a4; sa[lane * 8 + 5] = a5;
  sa[lane * 8 + 6] = a6; sa[lane * 8 + 7] = a7;
  __syncthreads();
  if (lane == 0) {
    int tl = tgt_len[n];
    double v = sa[2 * tl - 1] + sa[2 * tl];
    int ee;
    double m = frexp(v, &ee);
    nll_out[n] = -LN2_ * ((float)(Etot + ee) + log2f((float)m));
  }
}

__global__ void k_final(const float* __restrict__ nll,
                        const int* __restrict__ tgt_len,
                        float* __restrict__ out) {
  int lane = threadIdx.x;
  float v = 0.0f;
  if (lane < N_) v = nll[lane] / (float)tgt_len[lane];
#pragma unroll
  for (int i = 1; i < 64; i <<= 1) v += __shfl_xor(v, i);
  if (lane == 0) out[0] = v * (1.0f / N_);
}

__global__ void k_sentinel(float* out) { out[0] = -12345.0f; }

extern "C" void kernel_launch(void* const* d_in, const int* in_sizes, int n_in,
                              void* d_out, int out_size, void* d_ws, size_t ws_size,
                              hipStream_t stream) {
  const float* logits = (const float*)d_in[0];
  const int* targets  = (const int*)d_in[1];
  const int* in_len   = (const int*)d_in[2];
  const int* tgt_len  = (const int*)d_in[3];
  float* out = (float*)d_out;

  size_t gbytes = (size_t)N_ * T_ * LP_ * sizeof(float);  // ~104.9 MB
  if (ws_size < gbytes + 256) {
    k_sentinel<<<1, 1, 0, stream>>>(out);
    return;
  }
  float* G = (float*)d_ws;
  float* nll = (float*)((char*)d_ws + gbytes);

  k_softmax_gather<<<(N_ * T_) / 4, 256, 0, stream>>>(logits, targets, tgt_len, G);
  k_ctc<<<N_, 64, 0, stream>>>(G, targets, in_len, tgt_len, nll);
  k_final<<<1, 64, 0, stream>>>(nll, tgt_len, out);
}